// Round 17
// baseline (76.523 us; speedup 1.0000x reference)
//
#include <hip/hip_runtime.h>
#include <math.h>

#define H   128
#define NS  1024
#define NE  512
#define M   1024
#define K2  2.8853900817779268f   // 2*log2(e): tanh(x) = 1 - 2/(1+exp2(K2*x))

__device__ __forceinline__ float exp2_fast(float x) {
#if __has_builtin(__builtin_amdgcn_exp2f)
    return __builtin_amdgcn_exp2f(x);
#else
    return __expf(x * 0.6931471805599453f);
#endif
}

__device__ __forceinline__ float fast_tanh(float x) {
    float e = __expf(2.0f * x);
    float r = __builtin_amdgcn_rcpf(1.0f + e);
    return 1.0f - 2.0f * r;
}

// ---- transpose (+K2 scale) the weight matrices ---------------------------
__global__ __launch_bounds__(256) void k_tr(const float* __restrict__ Wc_s,
                                            const float* __restrict__ Wc_e,
                                            const float* __restrict__ W_lin,
                                            float* __restrict__ WT_s1, float* __restrict__ WT_s2,
                                            float* __restrict__ WT_e1, float* __restrict__ WT_e2,
                                            float* __restrict__ WT_lin) {
    int idx = blockIdx.x * 256 + threadIdx.x;
    if (idx < 65536) {
        int t = idx >> 14, r = idx & 16383, k = r >> 7, hh = r & 127;
        const float* src = (t < 2) ? Wc_s : Wc_e;
        int off = (t & 1) * H;
        float v = K2 * src[hh * 256 + off + k];
        float* dst = (t == 0) ? WT_s1 : (t == 1) ? WT_s2 : (t == 2) ? WT_e1 : WT_e2;
        dst[r] = v;
    } else {
        int j2 = idx - 65536;             // [0, 49152)
        int k = j2 >> 7, a = j2 & 127;
        WT_lin[j2] = W_lin[a * 384 + k];
    }
}

// ---- projections -> exp2 domain ------------------------------------------
__global__ __launch_bounds__(256) void k_proj(const float* __restrict__ stmts,
                                              const float* __restrict__ eres,
                                              const float* __restrict__ attender,
                                              const float* __restrict__ WT_s1,
                                              const float* __restrict__ WT_s2,
                                              const float* __restrict__ WT_e1,
                                              const float* __restrict__ WT_e2,
                                              const float* __restrict__ bc_s,
                                              const float* __restrict__ bc_e,
                                              float* __restrict__ EAT_s, float* __restrict__ EB_s,
                                              float* __restrict__ EAT_e, float* __restrict__ EB_e) {
    __shared__ float xr[16][H];
    __shared__ float red[16][H];
    int b   = blockIdx.x;
    int tid = threadIdx.x;
    int t    = tid & 127;
    int half = tid >> 7;

    if (b < 96) {
        const float *X, *WT, *bias; float* OT; int r0, N;
        if (b < 64) { X = stmts; WT = WT_s1; bias = bc_s; OT = EAT_s; r0 = b * 16;        N = NS; }
        else        { X = eres;  WT = WT_e1; bias = bc_e; OT = EAT_e; r0 = (b - 64) * 16; N = NE; }
        for (int i = tid; i < 16 * H; i += 256) xr[i >> 7][i & 127] = X[(r0 + (i >> 7)) * H + (i & 127)];
        __syncthreads();
        float b0 = (half == 0) ? K2 * bias[t] : 0.0f;
        float acc[16];
        #pragma unroll
        for (int r = 0; r < 16; ++r) acc[r] = b0;
        int k0 = half * 64;
        #pragma unroll 4
        for (int k = k0; k < k0 + 64; ++k) {
            float wv = WT[k * H + t];
            #pragma unroll
            for (int r = 0; r < 16; ++r) acc[r] += xr[r][k] * wv;
        }
        if (half) {
            #pragma unroll
            for (int r = 0; r < 16; ++r) red[r][t] = acc[r];
        }
        __syncthreads();
        if (!half) {
            #pragma unroll
            for (int r = 0; r < 16; ++r) xr[r][t] = exp2_fast(acc[r] + red[r][t]);
        }
        __syncthreads();
        {
            int hh  = tid >> 1;
            int seg = (tid & 1) * 8;
            float4 v0 = make_float4(xr[seg + 0][hh], xr[seg + 1][hh], xr[seg + 2][hh], xr[seg + 3][hh]);
            float4 v1 = make_float4(xr[seg + 4][hh], xr[seg + 5][hh], xr[seg + 6][hh], xr[seg + 7][hh]);
            *(float4*)(OT + (size_t)hh * N + r0 + seg)     = v0;
            *(float4*)(OT + (size_t)hh * N + r0 + seg + 4) = v1;
        }
    } else {
        int b2 = b - 96;
        const float* WT = (b2 < 256) ? WT_s2 : WT_e2;
        float* O        = (b2 < 256) ? EB_s : EB_e;
        int r0          = (b2 & 255) * 4;
        float* xf = &xr[0][0];
        xf[tid]       = attender[r0 * H + tid];
        xf[tid + 256] = attender[r0 * H + 256 + tid];
        __syncthreads();
        float acc[4] = {0.f, 0.f, 0.f, 0.f};
        int k0 = half * 64;
        #pragma unroll 8
        for (int k = k0; k < k0 + 64; ++k) {
            float wv = WT[k * H + t];
            #pragma unroll
            for (int r = 0; r < 4; ++r) acc[r] += xf[r * H + k] * wv;
        }
        if (half) {
            #pragma unroll
            for (int r = 0; r < 4; ++r) red[r][t] = acc[r];
        }
        __syncthreads();
        if (!half) {
            #pragma unroll
            for (int r = 0; r < 4; ++r) O[(r0 + r) * H + t] = exp2_fast(acc[r] + red[r][t]);
        }
    }
}

// ---- fused score + softmax + context --------------------------------------
// score = -2 * sum_h ws[h]/(1+Ea*Eb)   (softmax-invariant const dropped)
// TMD=2 m's/block, 512 threads, grid 1024 -> 4 blocks/CU = 32 waves/CU (max).
// EB read via uniform (scalar) loads -- no LDS stage, no barrier. TLP covers
// global-load latency (no explicit prefetch needed at 8 waves/SIMD).
#define PAIR(eax, eay, ebx, eby, wx, wy, accv)                 \
    { float q0 = fmaf(eax, ebx, 1.0f);                         \
      float q1 = fmaf(eay, eby, 1.0f);                         \
      float nn = wx * q1; nn = fmaf(wy, q0, nn);               \
      float rr = __builtin_amdgcn_rcpf(q0 * q1);               \
      accv = fmaf(nn, rr, accv); }

__global__ __launch_bounds__(512, 8) void k_score_ctx(const float* __restrict__ EAT_s,
                                                      const float* __restrict__ EB_s,
                                                      const float* __restrict__ ws_s,
                                                      const float* __restrict__ EAT_e,
                                                      const float* __restrict__ EB_e,
                                                      const float* __restrict__ ws_e,
                                                      const float* __restrict__ stmts,
                                                      const float* __restrict__ eres,
                                                      float* __restrict__ ctx_s,
                                                      float* __restrict__ ctx_e) {
    __shared__ float wbuf[1024][2];     // 8 KB (e-blocks use rows 0..511)
    __shared__ float part[4][2][H];     // 4 KB
    __shared__ float scrm[8][2], scrs[8][2], rzl[2];

    int b = blockIdx.x;                 // 0..1023
    bool is_e = (b >= 512);
    int m0 = (is_e ? (b - 512) : b) * 2;
    const float* EAT = is_e ? EAT_e : EAT_s;
    const float* EB  = is_e ? EB_e  : EB_s;
    const float* wsv = is_e ? ws_e  : ws_s;
    const float* X   = is_e ? eres  : stmts;
    float* ctxout    = is_e ? ctx_e : ctx_s;
    int N    = is_e ? NE : NS;
    int ROWS = is_e ? 1 : 2;
    int t = threadIdx.x;

    const float* eb0 = EB + (size_t)m0 * H;        // uniform
    const float* eb1 = EB + (size_t)(m0 + 1) * H;  // uniform

    float acc[2][2] = {{0.f, 0.f}, {0.f, 0.f}};
    for (int ch = 0; ch < 16; ++ch) {
        int h0 = ch * 8;
        float a0[8], a1[8];
        #pragma unroll
        for (int k = 0; k < 8; ++k) a0[k] = EAT[(size_t)(h0 + k) * N + t];
        if (ROWS > 1) {
            #pragma unroll
            for (int k = 0; k < 8; ++k) a1[k] = EAT[(size_t)(h0 + k) * N + t + 512];
        }
        float wv[8], b0[8], b1[8];
        #pragma unroll
        for (int k = 0; k < 8; ++k) {
            wv[k] = wsv[h0 + k];      // uniform -> s_load
            b0[k] = eb0[h0 + k];      // uniform -> s_load
            b1[k] = eb1[h0 + k];      // uniform -> s_load
        }
        PAIR(a0[0], a0[1], b0[0], b0[1], wv[0], wv[1], acc[0][0]);
        PAIR(a0[2], a0[3], b0[2], b0[3], wv[2], wv[3], acc[0][0]);
        PAIR(a0[4], a0[5], b0[4], b0[5], wv[4], wv[5], acc[0][0]);
        PAIR(a0[6], a0[7], b0[6], b0[7], wv[6], wv[7], acc[0][0]);
        PAIR(a0[0], a0[1], b1[0], b1[1], wv[0], wv[1], acc[0][1]);
        PAIR(a0[2], a0[3], b1[2], b1[3], wv[2], wv[3], acc[0][1]);
        PAIR(a0[4], a0[5], b1[4], b1[5], wv[4], wv[5], acc[0][1]);
        PAIR(a0[6], a0[7], b1[6], b1[7], wv[6], wv[7], acc[0][1]);
        if (ROWS > 1) {
            PAIR(a1[0], a1[1], b0[0], b0[1], wv[0], wv[1], acc[1][0]);
            PAIR(a1[2], a1[3], b0[2], b0[3], wv[2], wv[3], acc[1][0]);
            PAIR(a1[4], a1[5], b0[4], b0[5], wv[4], wv[5], acc[1][0]);
            PAIR(a1[6], a1[7], b0[6], b0[7], wv[6], wv[7], acc[1][0]);
            PAIR(a1[0], a1[1], b1[0], b1[1], wv[0], wv[1], acc[1][1]);
            PAIR(a1[2], a1[3], b1[2], b1[3], wv[2], wv[3], acc[1][1]);
            PAIR(a1[4], a1[5], b1[4], b1[5], wv[4], wv[5], acc[1][1]);
            PAIR(a1[6], a1[7], b1[6], b1[7], wv[6], wv[7], acc[1][1]);
        }
    }

    // ---- block-wide max & sum per mj ----
    int wave = t >> 6;
    float mx[2];
    for (int mj = 0; mj < 2; ++mj) {
        float v = -2.0f * acc[0][mj];
        if (ROWS > 1) v = fmaxf(v, -2.0f * acc[1][mj]);
        mx[mj] = v;
    }
    #pragma unroll
    for (int off = 32; off > 0; off >>= 1)
        for (int mj = 0; mj < 2; ++mj) mx[mj] = fmaxf(mx[mj], __shfl_xor(mx[mj], off, 64));
    if ((t & 63) == 0) {
        for (int mj = 0; mj < 2; ++mj) scrm[wave][mj] = mx[mj];
    }
    __syncthreads();
    for (int mj = 0; mj < 2; ++mj) {
        float r = scrm[0][mj];
        for (int i = 1; i < 8; ++i) r = fmaxf(r, scrm[i][mj]);
        mx[mj] = r;
    }

    float w0[2], w1[2], sm[2];
    for (int mj = 0; mj < 2; ++mj) {
        w0[mj] = __expf(fmaf(-2.0f, acc[0][mj], -mx[mj]));
        sm[mj] = w0[mj];
        if (ROWS > 1) { w1[mj] = __expf(fmaf(-2.0f, acc[1][mj], -mx[mj])); sm[mj] += w1[mj]; }
    }
    #pragma unroll
    for (int off = 32; off > 0; off >>= 1)
        for (int mj = 0; mj < 2; ++mj) sm[mj] += __shfl_xor(sm[mj], off, 64);
    if ((t & 63) == 0) {
        for (int mj = 0; mj < 2; ++mj) scrs[wave][mj] = sm[mj];
    }

    // stash w into LDS (never to global)
    wbuf[t][0] = w0[0];
    wbuf[t][1] = w0[1];
    if (ROWS > 1) { wbuf[t + 512][0] = w1[0]; wbuf[t + 512][1] = w1[1]; }
    __syncthreads();
    if (t < 2) {
        float s = scrs[0][t];
        for (int i = 1; i < 8; ++i) s += scrs[i][t];
        rzl[t] = __builtin_amdgcn_rcpf(s);
    }
    __syncthreads();

    // ---- ctx: 4 h-groups of 128, each covers N/4 rows ----
    {
        int h = t & 127;
        int g = t >> 7;                 // 0..3
        int CH = N >> 2;                // 256 (s) or 128 (e)
        const float* Xb = X + (size_t)(g * CH) * H + h;
        const float* wb = &wbuf[g * CH][0];
        float c0 = 0.f, c1 = 0.f;
        #pragma unroll 8
        for (int nn = 0; nn < CH; ++nn) {
            float x = Xb[(size_t)nn * H];
            float2 w2 = *(const float2*)(wb + nn * 2);   // broadcast
            c0 += w2.x * x;
            c1 += w2.y * x;
        }
        part[g][0][h] = c0;
        part[g][1][h] = c1;
    }
    __syncthreads();
    if (t < 2 * H) {
        int mj = t >> 7, h = t & 127;
        float s = part[0][mj][h] + part[1][mj][h] + part[2][mj][h] + part[3][mj][h];
        ctxout[(size_t)(m0 + mj) * H + h] = s * rzl[mj];
    }
}

// ---- final MLP + coherence -------------------------------------------------
__global__ __launch_bounds__(512) void k_mlp(const float* __restrict__ attender,
                                             const float* __restrict__ ctx_s,
                                             const float* __restrict__ ctx_e,
                                             const float* __restrict__ WT_lin,
                                             const float* __restrict__ b_lin,
                                             const float* __restrict__ W_coh,
                                             const float* __restrict__ b_coh,
                                             float* __restrict__ out) {
    __shared__ float feats[4][3 * H];   // 6 KB
    __shared__ float red2[8];
    int m0 = blockIdx.x * 4;
    int t  = threadIdx.x;

    for (int i = t; i < 4 * 3 * H; i += 512) {
        int r = i / (3 * H), c = i % (3 * H);
        float v;
        if (c < H)            v = attender[(size_t)(m0 + r) * H + c];
        else if (c < 2 * H)   v = ctx_s[(size_t)(m0 + r) * H + (c - H)];
        else                  v = ctx_e[(size_t)(m0 + r) * H + (c - 2 * H)];
        feats[r][c] = v;
    }
    __syncthreads();

    int a  = t & 127;
    int jm = t >> 7;
    float acc = b_lin[a];
    #pragma unroll 8
    for (int k = 0; k < 3 * H; ++k)
        acc += feats[jm][k] * WT_lin[k * H + a];
    float v = fast_tanh(acc) * W_coh[a];
    #pragma unroll
    for (int off = 32; off > 0; off >>= 1) v += __shfl_down(v, off, 64);
    if ((t & 63) == 0) red2[t >> 6] = v;
    __syncthreads();
    if (t < 4) out[m0 + t] = red2[2 * t] + red2[2 * t + 1] + b_coh[0];
}

extern "C" void kernel_launch(void* const* d_in, const int* in_sizes, int n_in,
                              void* d_out, int out_size, void* d_ws, size_t ws_size,
                              hipStream_t stream) {
    const float* stmts    = (const float*)d_in[0];
    const float* eres     = (const float*)d_in[1];
    const float* attender = (const float*)d_in[2];
    const float* Wc_s     = (const float*)d_in[3];
    const float* bc_s     = (const float*)d_in[4];
    const float* ws_s     = (const float*)d_in[5];
    const float* Wc_e     = (const float*)d_in[7];
    const float* bc_e     = (const float*)d_in[8];
    const float* ws_e     = (const float*)d_in[9];
    const float* W_lin    = (const float*)d_in[11];
    const float* b_lin    = (const float*)d_in[12];
    const float* W_coh    = (const float*)d_in[13];
    const float* b_coh    = (const float*)d_in[14];
    float* out = (float*)d_out;

    float* ws    = (float*)d_ws;
    float* WT_s1 = ws;
    float* WT_s2 = WT_s1 + H * H;
    float* WT_e1 = WT_s2 + H * H;
    float* WT_e2 = WT_e1 + H * H;
    float* WT_li = WT_e2 + H * H;             // 384*128
    float* EAT_s = WT_li + 3 * H * H;         // [H][NS]
    float* EB_s  = EAT_s + NS * H;
    float* EAT_e = EB_s + M * H;              // [H][NE]
    float* EB_e  = EAT_e + NE * H;
    float* c_s   = EB_e + M * H;              // ctx_s [M][H]
    float* c_e   = c_s + (size_t)M * H;       // ctx_e [M][H]

    k_tr<<<448, 256, 0, stream>>>(Wc_s, Wc_e, W_lin, WT_s1, WT_s2, WT_e1, WT_e2, WT_li);
    k_proj<<<608, 256, 0, stream>>>(stmts, eres, attender, WT_s1, WT_s2, WT_e1, WT_e2,
                                    bc_s, bc_e, EAT_s, EB_s, EAT_e, EB_e);
    k_score_ctx<<<1024, 512, 0, stream>>>(EAT_s, EB_s, ws_s, EAT_e, EB_e, ws_e,
                                          stmts, eres, c_s, c_e);
    k_mlp<<<M / 4, 512, 0, stream>>>(attender, c_s, c_e, WT_li, b_lin, W_coh, b_coh, out);
}

// Round 18
// 65.622 us; speedup vs baseline: 1.1661x; 1.1661x over previous
//
#include <hip/hip_runtime.h>
#include <math.h>

#define H   128
#define NS  1024
#define NE  512
#define M   1024
#define K2  2.8853900817779268f   // 2*log2(e): tanh(x) = 1 - 2/(1+exp2(K2*x))

typedef float v4 __attribute__((ext_vector_type(4)));
typedef float v2 __attribute__((ext_vector_type(2)));

__device__ __forceinline__ float exp2_fast(float x) {
#if __has_builtin(__builtin_amdgcn_exp2f)
    return __builtin_amdgcn_exp2f(x);
#else
    return __expf(x * 0.6931471805599453f);
#endif
}

__device__ __forceinline__ float fast_tanh(float x) {
    float e = __expf(2.0f * x);
    float r = __builtin_amdgcn_rcpf(1.0f + e);
    return 1.0f - 2.0f * r;
}

// ---- transpose (+K2 scale) the weight matrices ---------------------------
__global__ __launch_bounds__(256) void k_tr(const float* __restrict__ Wc_s,
                                            const float* __restrict__ Wc_e,
                                            const float* __restrict__ W_lin,
                                            float* __restrict__ WT_s1, float* __restrict__ WT_s2,
                                            float* __restrict__ WT_e1, float* __restrict__ WT_e2,
                                            float* __restrict__ WT_lin) {
    int idx = blockIdx.x * 256 + threadIdx.x;
    if (idx < 65536) {
        int t = idx >> 14, r = idx & 16383, k = r >> 7, hh = r & 127;
        const float* src = (t < 2) ? Wc_s : Wc_e;
        int off = (t & 1) * H;
        float v = K2 * src[hh * 256 + off + k];
        float* dst = (t == 0) ? WT_s1 : (t == 1) ? WT_s2 : (t == 2) ? WT_e1 : WT_e2;
        dst[r] = v;
    } else {
        int j2 = idx - 65536;             // [0, 49152)
        int k = j2 >> 7, a = j2 & 127;
        WT_lin[j2] = W_lin[a * 384 + k];
    }
}

// ---- projections -> exp2 domain ------------------------------------------
__global__ __launch_bounds__(256) void k_proj(const float* __restrict__ stmts,
                                              const float* __restrict__ eres,
                                              const float* __restrict__ attender,
                                              const float* __restrict__ WT_s1,
                                              const float* __restrict__ WT_s2,
                                              const float* __restrict__ WT_e1,
                                              const float* __restrict__ WT_e2,
                                              const float* __restrict__ bc_s,
                                              const float* __restrict__ bc_e,
                                              float* __restrict__ EAT_s, float* __restrict__ EB_s,
                                              float* __restrict__ EAT_e, float* __restrict__ EB_e) {
    __shared__ float xr[16][H];
    __shared__ float red[16][H];
    int b   = blockIdx.x;
    int tid = threadIdx.x;
    int t    = tid & 127;
    int half = tid >> 7;

    if (b < 96) {
        const float *X, *WT, *bias; float* OT; int r0, N;
        if (b < 64) { X = stmts; WT = WT_s1; bias = bc_s; OT = EAT_s; r0 = b * 16;        N = NS; }
        else        { X = eres;  WT = WT_e1; bias = bc_e; OT = EAT_e; r0 = (b - 64) * 16; N = NE; }
        for (int i = tid; i < 16 * H; i += 256) xr[i >> 7][i & 127] = X[(r0 + (i >> 7)) * H + (i & 127)];
        __syncthreads();
        float b0 = (half == 0) ? K2 * bias[t] : 0.0f;
        float acc[16];
        #pragma unroll
        for (int r = 0; r < 16; ++r) acc[r] = b0;
        int k0 = half * 64;
        #pragma unroll 4
        for (int k = k0; k < k0 + 64; ++k) {
            float wv = WT[k * H + t];
            #pragma unroll
            for (int r = 0; r < 16; ++r) acc[r] += xr[r][k] * wv;
        }
        if (half) {
            #pragma unroll
            for (int r = 0; r < 16; ++r) red[r][t] = acc[r];
        }
        __syncthreads();
        if (!half) {
            #pragma unroll
            for (int r = 0; r < 16; ++r) xr[r][t] = exp2_fast(acc[r] + red[r][t]);
        }
        __syncthreads();
        {
            int hh  = tid >> 1;
            int seg = (tid & 1) * 8;
            float4 v0 = make_float4(xr[seg + 0][hh], xr[seg + 1][hh], xr[seg + 2][hh], xr[seg + 3][hh]);
            float4 v1 = make_float4(xr[seg + 4][hh], xr[seg + 5][hh], xr[seg + 6][hh], xr[seg + 7][hh]);
            *(float4*)(OT + (size_t)hh * N + r0 + seg)     = v0;
            *(float4*)(OT + (size_t)hh * N + r0 + seg + 4) = v1;
        }
    } else {
        int b2 = b - 96;
        const float* WT = (b2 < 256) ? WT_s2 : WT_e2;
        float* O        = (b2 < 256) ? EB_s : EB_e;
        int r0          = (b2 & 255) * 4;
        float* xf = &xr[0][0];
        xf[tid]       = attender[r0 * H + tid];
        xf[tid + 256] = attender[r0 * H + 256 + tid];
        __syncthreads();
        float acc[4] = {0.f, 0.f, 0.f, 0.f};
        int k0 = half * 64;
        #pragma unroll 8
        for (int k = k0; k < k0 + 64; ++k) {
            float wv = WT[k * H + t];
            #pragma unroll
            for (int r = 0; r < 4; ++r) acc[r] += xf[r * H + k] * wv;
        }
        if (half) {
            #pragma unroll
            for (int r = 0; r < 4; ++r) red[r][t] = acc[r];
        }
        __syncthreads();
        if (!half) {
            #pragma unroll
            for (int r = 0; r < 4; ++r) O[(r0 + r) * H + t] = exp2_fast(acc[r] + red[r][t]);
        }
    }
}

// ---- fused score + softmax + context --------------------------------------
// score = -2 * sum_h ws[h]/(1+Ea*Eb)   (softmax-invariant const dropped)
// TMD=4 m's/block, 512 thr, grid 512. Thread owns 4 consecutive n (float4
// loads; e-blocks: 2 n via float2) and HALF the h-range (hg = t>>8); halves
// combine via conflict-free transposed LDS. B/ws via uniform scalar loads.
#define PAIR(eax, eay, ebx, eby, wx, wy, accv)                 \
    { float q0 = fmaf(eax, ebx, 1.0f);                         \
      float q1 = fmaf(eay, eby, 1.0f);                         \
      float nn = wx * q1; nn = fmaf(wy, q0, nn);               \
      float rr = __builtin_amdgcn_rcpf(q0 * q1);               \
      accv = fmaf(nn, rr, accv); }

__global__ __launch_bounds__(512, 4) void k_score_ctx(const float* __restrict__ EAT_s,
                                                      const float* __restrict__ EB_s,
                                                      const float* __restrict__ ws_s,
                                                      const float* __restrict__ EAT_e,
                                                      const float* __restrict__ EB_e,
                                                      const float* __restrict__ ws_e,
                                                      const float* __restrict__ stmts,
                                                      const float* __restrict__ eres,
                                                      float* __restrict__ ctx_s,
                                                      float* __restrict__ ctx_e) {
    __shared__ float partial[16][257];  // combine buffer (row = i*4+j), pad ok
    __shared__ float wbuf[1024][4];     // w values (e-blocks: rows 0..511)
    __shared__ float part[4][4][H];     // ctx partials
    __shared__ float scrm[4][4], scrs[4][4], rzl[4];

    int b = blockIdx.x;                 // 0..511
    bool is_e = (b >= 256);
    int m0 = (is_e ? (b - 256) : b) * 4;
    const float* EAT = is_e ? EAT_e : EAT_s;
    const float* EB  = is_e ? EB_e  : EB_s;
    const float* wsv = is_e ? ws_e  : ws_s;
    const float* X   = is_e ? eres  : stmts;
    float* ctxout    = is_e ? ctx_e : ctx_s;
    int N  = is_e ? NE : NS;
    int NL = is_e ? 2 : 4;              // n's per thread
    int t  = threadIdx.x;
    int tq = t & 255;
    int hg = t >> 8;                    // 0/1: h-half
    int hbase = hg * 64;

    float acc[4][4] = {{0.f,0.f,0.f,0.f},{0.f,0.f,0.f,0.f},
                       {0.f,0.f,0.f,0.f},{0.f,0.f,0.f,0.f}};

    if (!is_e) {
        const float* base = EAT + 4 * tq;
        v4 a[4], an[4];
        #pragma unroll
        for (int k = 0; k < 4; ++k) a[k] = *(const v4*)(base + (size_t)(hbase + k) * NS);
        for (int ch = 0; ch < 16; ++ch) {
            int h0 = hbase + ch * 4;
            if (ch < 15) {
                #pragma unroll
                for (int k = 0; k < 4; ++k)
                    an[k] = *(const v4*)(base + (size_t)(h0 + 4 + k) * NS);
            }
            float wv[4];
            #pragma unroll
            for (int k = 0; k < 4; ++k) wv[k] = wsv[h0 + k];         // uniform
            #pragma unroll
            for (int mj = 0; mj < 4; ++mj) {
                float b0 = EB[(size_t)(m0 + mj) * H + h0 + 0];       // uniform
                float b1 = EB[(size_t)(m0 + mj) * H + h0 + 1];
                float b2 = EB[(size_t)(m0 + mj) * H + h0 + 2];
                float b3 = EB[(size_t)(m0 + mj) * H + h0 + 3];
                #pragma unroll
                for (int i = 0; i < 4; ++i) {
                    PAIR(a[0][i], a[1][i], b0, b1, wv[0], wv[1], acc[i][mj]);
                    PAIR(a[2][i], a[3][i], b2, b3, wv[2], wv[3], acc[i][mj]);
                }
            }
            #pragma unroll
            for (int k = 0; k < 4; ++k) a[k] = an[k];
        }
    } else {
        const float* base = EAT + 2 * tq;
        v2 a[4], an[4];
        #pragma unroll
        for (int k = 0; k < 4; ++k) a[k] = *(const v2*)(base + (size_t)(hbase + k) * NE);
        for (int ch = 0; ch < 16; ++ch) {
            int h0 = hbase + ch * 4;
            if (ch < 15) {
                #pragma unroll
                for (int k = 0; k < 4; ++k)
                    an[k] = *(const v2*)(base + (size_t)(h0 + 4 + k) * NE);
            }
            float wv[4];
            #pragma unroll
            for (int k = 0; k < 4; ++k) wv[k] = wsv[h0 + k];
            #pragma unroll
            for (int mj = 0; mj < 4; ++mj) {
                float b0 = EB[(size_t)(m0 + mj) * H + h0 + 0];
                float b1 = EB[(size_t)(m0 + mj) * H + h0 + 1];
                float b2 = EB[(size_t)(m0 + mj) * H + h0 + 2];
                float b3 = EB[(size_t)(m0 + mj) * H + h0 + 3];
                #pragma unroll
                for (int i = 0; i < 2; ++i) {
                    PAIR(a[0][i], a[1][i], b0, b1, wv[0], wv[1], acc[i][mj]);
                    PAIR(a[2][i], a[3][i], b2, b3, wv[2], wv[3], acc[i][mj]);
                }
            }
            #pragma unroll
            for (int k = 0; k < 4; ++k) a[k] = an[k];
        }
    }

    // ---- combine h-halves (hg1 -> LDS, hg0 adds) ----
    if (hg) {
        for (int i = 0; i < NL; ++i)
            #pragma unroll
            for (int j = 0; j < 4; ++j) partial[i * 4 + j][tq] = acc[i][j];
    }
    __syncthreads();
    int wave = t >> 6;                  // hg0 threads: waves 0..3
    if (!hg) {
        for (int i = 0; i < NL; ++i)
            #pragma unroll
            for (int j = 0; j < 4; ++j) acc[i][j] += partial[i * 4 + j][tq];
        float mx[4];
        #pragma unroll
        for (int j = 0; j < 4; ++j) {
            float v = -2.0f * acc[0][j];
            for (int i = 1; i < NL; ++i) v = fmaxf(v, -2.0f * acc[i][j]);
            mx[j] = v;
        }
        #pragma unroll
        for (int off = 32; off > 0; off >>= 1)
            for (int j = 0; j < 4; ++j) mx[j] = fmaxf(mx[j], __shfl_xor(mx[j], off, 64));
        if ((t & 63) == 0) {
            for (int j = 0; j < 4; ++j) scrm[wave][j] = mx[j];
        }
    }
    __syncthreads();
    if (!hg) {
        float mx[4], sm[4];
        #pragma unroll
        for (int j = 0; j < 4; ++j)
            mx[j] = fmaxf(fmaxf(scrm[0][j], scrm[1][j]), fmaxf(scrm[2][j], scrm[3][j]));
        #pragma unroll
        for (int j = 0; j < 4; ++j) sm[j] = 0.f;
        float w[4][4];
        for (int i = 0; i < NL; ++i) {
            #pragma unroll
            for (int j = 0; j < 4; ++j) {
                w[i][j] = __expf(fmaf(-2.0f, acc[i][j], -mx[j]));
                sm[j] += w[i][j];
            }
        }
        #pragma unroll
        for (int off = 32; off > 0; off >>= 1)
            for (int j = 0; j < 4; ++j) sm[j] += __shfl_xor(sm[j], off, 64);
        if ((t & 63) == 0) {
            for (int j = 0; j < 4; ++j) scrs[wave][j] = sm[j];
        }
        for (int i = 0; i < NL; ++i)
            *(v4*)&wbuf[NL * tq + i][0] = (v4){w[i][0], w[i][1], w[i][2], w[i][3]};
    }
    __syncthreads();
    if (t < 4)
        rzl[t] = __builtin_amdgcn_rcpf(scrs[0][t] + scrs[1][t] + scrs[2][t] + scrs[3][t]);
    __syncthreads();

    // ---- ctx: 4 h-groups of 128, each covers N/4 rows ----
    {
        int h = t & 127;
        int g = t >> 7;                 // 0..3
        int CH = N >> 2;                // 256 (s) or 128 (e)
        const float* Xb = X + (size_t)(g * CH) * H + h;
        const float* wb = &wbuf[g * CH][0];
        float c[4] = {0.f, 0.f, 0.f, 0.f};
        #pragma unroll 8
        for (int nn = 0; nn < CH; ++nn) {
            float x = Xb[(size_t)nn * H];
            float4 w4 = *(const float4*)(wb + nn * 4);   // broadcast b128
            c[0] += w4.x * x; c[1] += w4.y * x;
            c[2] += w4.z * x; c[3] += w4.w * x;
        }
        #pragma unroll
        for (int mj = 0; mj < 4; ++mj) part[g][mj][h] = c[mj];
    }
    __syncthreads();
    {
        int mj = t >> 7, h = t & 127;
        float s = part[0][mj][h] + part[1][mj][h] + part[2][mj][h] + part[3][mj][h];
        ctxout[(size_t)(m0 + mj) * H + h] = s * rzl[mj];
    }
}

// ---- final MLP + coherence -------------------------------------------------
__global__ __launch_bounds__(512) void k_mlp(const float* __restrict__ attender,
                                             const float* __restrict__ ctx_s,
                                             const float* __restrict__ ctx_e,
                                             const float* __restrict__ WT_lin,
                                             const float* __restrict__ b_lin,
                                             const float* __restrict__ W_coh,
                                             const float* __restrict__ b_coh,
                                             float* __restrict__ out) {
    __shared__ float feats[4][3 * H];   // 6 KB
    __shared__ float red2[8];
    int m0 = blockIdx.x * 4;
    int t  = threadIdx.x;

    for (int i = t; i < 4 * 3 * H; i += 512) {
        int r = i / (3 * H), c = i % (3 * H);
        float v;
        if (c < H)            v = attender[(size_t)(m0 + r) * H + c];
        else if (c < 2 * H)   v = ctx_s[(size_t)(m0 + r) * H + (c - H)];
        else                  v = ctx_e[(size_t)(m0 + r) * H + (c - 2 * H)];
        feats[r][c] = v;
    }
    __syncthreads();

    int a  = t & 127;
    int jm = t >> 7;
    float acc = b_lin[a];
    #pragma unroll 8
    for (int k = 0; k < 3 * H; ++k)
        acc += feats[jm][k] * WT_lin[k * H + a];
    float v = fast_tanh(acc) * W_coh[a];
    #pragma unroll
    for (int off = 32; off > 0; off >>= 1) v += __shfl_down(v, off, 64);
    if ((t & 63) == 0) red2[t >> 6] = v;
    __syncthreads();
    if (t < 4) out[m0 + t] = red2[2 * t] + red2[2 * t + 1] + b_coh[0];
}

extern "C" void kernel_launch(void* const* d_in, const int* in_sizes, int n_in,
                              void* d_out, int out_size, void* d_ws, size_t ws_size,
                              hipStream_t stream) {
    const float* stmts    = (const float*)d_in[0];
    const float* eres     = (const float*)d_in[1];
    const float* attender = (const float*)d_in[2];
    const float* Wc_s     = (const float*)d_in[3];
    const float* bc_s     = (const float*)d_in[4];
    const float* ws_s     = (const float*)d_in[5];
    const float* Wc_e     = (const float*)d_in[7];
    const float* bc_e     = (const float*)d_in[8];
    const float* ws_e     = (const float*)d_in[9];
    const float* W_lin    = (const float*)d_in[11];
    const float* b_lin    = (const float*)d_in[12];
    const float* W_coh    = (const float*)d_in[13];
    const float* b_coh    = (const float*)d_in[14];
    float* out = (float*)d_out;

    float* ws    = (float*)d_ws;
    float* WT_s1 = ws;
    float* WT_s2 = WT_s1 + H * H;
    float* WT_e1 = WT_s2 + H * H;
    float* WT_e2 = WT_e1 + H * H;
    float* WT_li = WT_e2 + H * H;             // 384*128
    float* EAT_s = WT_li + 3 * H * H;         // [H][NS]
    float* EB_s  = EAT_s + NS * H;
    float* EAT_e = EB_s + M * H;              // [H][NE]
    float* EB_e  = EAT_e + NE * H;
    float* c_s   = EB_e + M * H;              // ctx_s [M][H]
    float* c_e   = c_s + (size_t)M * H;       // ctx_e [M][H]

    k_tr<<<448, 256, 0, stream>>>(Wc_s, Wc_e, W_lin, WT_s1, WT_s2, WT_e1, WT_e2, WT_li);
    k_proj<<<608, 256, 0, stream>>>(stmts, eres, attender, WT_s1, WT_s2, WT_e1, WT_e2,
                                    bc_s, bc_e, EAT_s, EB_s, EAT_e, EB_e);
    k_score_ctx<<<512, 512, 0, stream>>>(EAT_s, EB_s, ws_s, EAT_e, EB_e, ws_e,
                                         stmts, eres, c_s, c_e);
    k_mlp<<<M / 4, 512, 0, stream>>>(attender, c_s, c_e, WT_li, b_lin, W_coh, b_coh, out);
}

// Round 19
// 64.292 us; speedup vs baseline: 1.1902x; 1.0207x over previous
//
#include <hip/hip_runtime.h>
#include <math.h>

#define H   128
#define NS  1024
#define NE  512
#define M   1024
#define K2  2.8853900817779268f   // 2*log2(e)

typedef float v4 __attribute__((ext_vector_type(4)));
typedef float v2 __attribute__((ext_vector_type(2)));

__device__ __forceinline__ float exp2_fast(float x) {
#if __has_builtin(__builtin_amdgcn_exp2f)
    return __builtin_amdgcn_exp2f(x);
#else
    return __expf(x * 0.6931471805599453f);
#endif
}

__device__ __forceinline__ float fast_tanh(float x) {
    float e = __expf(2.0f * x);
    float r = __builtin_amdgcn_rcpf(1.0f + e);
    return 1.0f - 2.0f * r;
}

// ---- transpose (+K2 scale) the weight matrices ---------------------------
__global__ __launch_bounds__(256) void k_tr(const float* __restrict__ Wc_s,
                                            const float* __restrict__ Wc_e,
                                            const float* __restrict__ W_lin,
                                            float* __restrict__ WT_s1, float* __restrict__ WT_s2,
                                            float* __restrict__ WT_e1, float* __restrict__ WT_e2,
                                            float* __restrict__ WT_lin) {
    int idx = blockIdx.x * 256 + threadIdx.x;
    if (idx < 65536) {
        int t = idx >> 14, r = idx & 16383, k = r >> 7, hh = r & 127;
        const float* src = (t < 2) ? Wc_s : Wc_e;
        int off = (t & 1) * H;
        float v = K2 * src[hh * 256 + off + k];
        float* dst = (t == 0) ? WT_s1 : (t == 1) ? WT_s2 : (t == 2) ? WT_e1 : WT_e2;
        dst[r] = v;
    } else {
        int j2 = idx - 65536;             // [0, 49152)
        int k = j2 >> 7, a = j2 & 127;
        WT_lin[j2] = W_lin[a * 384 + k];
    }
}

// ---- projections -> exp2 domain ------------------------------------------
__global__ __launch_bounds__(256) void k_proj(const float* __restrict__ stmts,
                                              const float* __restrict__ eres,
                                              const float* __restrict__ attender,
                                              const float* __restrict__ WT_s1,
                                              const float* __restrict__ WT_s2,
                                              const float* __restrict__ WT_e1,
                                              const float* __restrict__ WT_e2,
                                              const float* __restrict__ bc_s,
                                              const float* __restrict__ bc_e,
                                              float* __restrict__ EAT_s, float* __restrict__ EB_s,
                                              float* __restrict__ EAT_e, float* __restrict__ EB_e) {
    __shared__ float xr[16][H];
    __shared__ float red[16][H];
    int b   = blockIdx.x;
    int tid = threadIdx.x;
    int t    = tid & 127;
    int half = tid >> 7;

    if (b < 96) {
        const float *X, *WT, *bias; float* OT; int r0, N;
        if (b < 64) { X = stmts; WT = WT_s1; bias = bc_s; OT = EAT_s; r0 = b * 16;        N = NS; }
        else        { X = eres;  WT = WT_e1; bias = bc_e; OT = EAT_e; r0 = (b - 64) * 16; N = NE; }
        for (int i = tid; i < 16 * H; i += 256) xr[i >> 7][i & 127] = X[(r0 + (i >> 7)) * H + (i & 127)];
        __syncthreads();
        float b0 = (half == 0) ? K2 * bias[t] : 0.0f;
        float acc[16];
        #pragma unroll
        for (int r = 0; r < 16; ++r) acc[r] = b0;
        int k0 = half * 64;
        #pragma unroll 4
        for (int k = k0; k < k0 + 64; ++k) {
            float wv = WT[k * H + t];
            #pragma unroll
            for (int r = 0; r < 16; ++r) acc[r] += xr[r][k] * wv;
        }
        if (half) {
            #pragma unroll
            for (int r = 0; r < 16; ++r) red[r][t] = acc[r];
        }
        __syncthreads();
        if (!half) {
            #pragma unroll
            for (int r = 0; r < 16; ++r) xr[r][t] = exp2_fast(acc[r] + red[r][t]);
        }
        __syncthreads();
        {
            int hh  = tid >> 1;
            int seg = (tid & 1) * 8;
            float4 v0 = make_float4(xr[seg + 0][hh], xr[seg + 1][hh], xr[seg + 2][hh], xr[seg + 3][hh]);
            float4 v1 = make_float4(xr[seg + 4][hh], xr[seg + 5][hh], xr[seg + 6][hh], xr[seg + 7][hh]);
            *(float4*)(OT + (size_t)hh * N + r0 + seg)     = v0;
            *(float4*)(OT + (size_t)hh * N + r0 + seg + 4) = v1;
        }
    } else {
        int b2 = b - 96;
        const float* WT = (b2 < 256) ? WT_s2 : WT_e2;
        float* O        = (b2 < 256) ? EB_s : EB_e;
        int r0          = (b2 & 255) * 4;
        float* xf = &xr[0][0];
        xf[tid]       = attender[r0 * H + tid];
        xf[tid + 256] = attender[r0 * H + 256 + tid];
        __syncthreads();
        float acc[4] = {0.f, 0.f, 0.f, 0.f};
        int k0 = half * 64;
        #pragma unroll 8
        for (int k = k0; k < k0 + 64; ++k) {
            float wv = WT[k * H + t];
            #pragma unroll
            for (int r = 0; r < 4; ++r) acc[r] += xf[r * H + k] * wv;
        }
        if (half) {
            #pragma unroll
            for (int r = 0; r < 4; ++r) red[r][t] = acc[r];
        }
        __syncthreads();
        if (!half) {
            #pragma unroll
            for (int r = 0; r < 4; ++r) O[(r0 + r) * H + t] = exp2_fast(acc[r] + red[r][t]);
        }
    }
}

// ---- fused score + softmax + context --------------------------------------
// score = -2 * sum_h ws[h]/(1+Ea*Eb)  (const dropped).  No max-subtraction:
// |score| <= 2*sum|ws| ~ 18, exp fits fp32 easily.  w = exp2(-K2*acc).
// QUAD: one rcp per 4 h's:  sum w_i/q_i = (n01*d23 + n23*d01)/(d01*d23).
#define QUAD(a0,a1,a2,a3, b0,b1,b2,b3, w0,w1,w2,w3, accv)              \
    { float q0 = fmaf(a0, b0, 1.0f), q1 = fmaf(a1, b1, 1.0f);          \
      float q2 = fmaf(a2, b2, 1.0f), q3 = fmaf(a3, b3, 1.0f);          \
      float d01 = q0 * q1, d23 = q2 * q3;                              \
      float n01 = w0 * q1; n01 = fmaf(w1, q0, n01);                    \
      float n23 = w2 * q3; n23 = fmaf(w3, q2, n23);                    \
      float nn = n01 * d23; nn = fmaf(n23, d01, nn);                   \
      float rr = __builtin_amdgcn_rcpf(d01 * d23);                     \
      accv = fmaf(nn, rr, accv); }

__global__ __launch_bounds__(512, 4) void k_score_ctx(const float* __restrict__ EAT_s,
                                                      const float* __restrict__ EB_s,
                                                      const float* __restrict__ ws_s,
                                                      const float* __restrict__ EAT_e,
                                                      const float* __restrict__ EB_e,
                                                      const float* __restrict__ ws_e,
                                                      const float* __restrict__ stmts,
                                                      const float* __restrict__ eres,
                                                      float* __restrict__ ctx_s,
                                                      float* __restrict__ ctx_e) {
    __shared__ float partial[16][257];  // h-half combine buffer
    __shared__ float wbuf[1024][4];     // w values (e-blocks: rows 0..511)
    __shared__ float part[4][4][H];     // ctx partials
    __shared__ float scrs[4][4], rzl[4];

    int b = blockIdx.x;                 // 0..511
    bool is_e = (b >= 256);
    int m0 = (is_e ? (b - 256) : b) * 4;
    const float* EAT = is_e ? EAT_e : EAT_s;
    const float* EB  = is_e ? EB_e  : EB_s;
    const float* wsv = is_e ? ws_e  : ws_s;
    const float* X   = is_e ? eres  : stmts;
    float* ctxout    = is_e ? ctx_e : ctx_s;
    int N  = is_e ? NE : NS;
    int NL = is_e ? 2 : 4;              // n's per thread
    int t  = threadIdx.x;
    int tq = t & 255;
    int hg = t >> 8;                    // 0/1: h-half
    int hbase = hg * 64;

    float acc[4][4] = {{0.f,0.f,0.f,0.f},{0.f,0.f,0.f,0.f},
                       {0.f,0.f,0.f,0.f},{0.f,0.f,0.f,0.f}};

    if (!is_e) {
        const float* base = EAT + 4 * tq;
        v4 a[4], an[4];
        #pragma unroll
        for (int k = 0; k < 4; ++k) a[k] = *(const v4*)(base + (size_t)(hbase + k) * NS);
        for (int ch = 0; ch < 16; ++ch) {
            int h0 = hbase + ch * 4;
            if (ch < 15) {
                #pragma unroll
                for (int k = 0; k < 4; ++k)
                    an[k] = *(const v4*)(base + (size_t)(h0 + 4 + k) * NS);
            }
            float wv[4];
            #pragma unroll
            for (int k = 0; k < 4; ++k) wv[k] = wsv[h0 + k];         // uniform
            #pragma unroll
            for (int mj = 0; mj < 4; ++mj) {
                float b0 = EB[(size_t)(m0 + mj) * H + h0 + 0];       // uniform
                float b1 = EB[(size_t)(m0 + mj) * H + h0 + 1];
                float b2 = EB[(size_t)(m0 + mj) * H + h0 + 2];
                float b3 = EB[(size_t)(m0 + mj) * H + h0 + 3];
                #pragma unroll
                for (int i = 0; i < 4; ++i)
                    QUAD(a[0][i], a[1][i], a[2][i], a[3][i],
                         b0, b1, b2, b3, wv[0], wv[1], wv[2], wv[3], acc[i][mj]);
            }
            #pragma unroll
            for (int k = 0; k < 4; ++k) a[k] = an[k];
        }
    } else {
        const float* base = EAT + 2 * tq;
        v2 a[4], an[4];
        #pragma unroll
        for (int k = 0; k < 4; ++k) a[k] = *(const v2*)(base + (size_t)(hbase + k) * NE);
        for (int ch = 0; ch < 16; ++ch) {
            int h0 = hbase + ch * 4;
            if (ch < 15) {
                #pragma unroll
                for (int k = 0; k < 4; ++k)
                    an[k] = *(const v2*)(base + (size_t)(h0 + 4 + k) * NE);
            }
            float wv[4];
            #pragma unroll
            for (int k = 0; k < 4; ++k) wv[k] = wsv[h0 + k];
            #pragma unroll
            for (int mj = 0; mj < 4; ++mj) {
                float b0 = EB[(size_t)(m0 + mj) * H + h0 + 0];
                float b1 = EB[(size_t)(m0 + mj) * H + h0 + 1];
                float b2 = EB[(size_t)(m0 + mj) * H + h0 + 2];
                float b3 = EB[(size_t)(m0 + mj) * H + h0 + 3];
                #pragma unroll
                for (int i = 0; i < 2; ++i)
                    QUAD(a[0][i], a[1][i], a[2][i], a[3][i],
                         b0, b1, b2, b3, wv[0], wv[1], wv[2], wv[3], acc[i][mj]);
            }
            #pragma unroll
            for (int k = 0; k < 4; ++k) a[k] = an[k];
        }
    }

    // ---- combine h-halves (hg1 -> LDS, hg0 adds), then exp + sum ----
    if (hg) {
        for (int i = 0; i < NL; ++i)
            #pragma unroll
            for (int j = 0; j < 4; ++j) partial[i * 4 + j][tq] = acc[i][j];
    }
    __syncthreads();
    int wave = t >> 6;                  // hg0 threads: waves 0..3
    if (!hg) {
        float w[4][4], sm[4];
        #pragma unroll
        for (int j = 0; j < 4; ++j) sm[j] = 0.f;
        for (int i = 0; i < NL; ++i) {
            #pragma unroll
            for (int j = 0; j < 4; ++j) {
                float a = acc[i][j] + partial[i * 4 + j][tq];
                w[i][j] = exp2_fast(-K2 * a);      // exp(score), no max-sub
                sm[j] += w[i][j];
            }
        }
        #pragma unroll
        for (int off = 32; off > 0; off >>= 1)
            for (int j = 0; j < 4; ++j) sm[j] += __shfl_xor(sm[j], off, 64);
        if ((t & 63) == 0) {
            for (int j = 0; j < 4; ++j) scrs[wave][j] = sm[j];
        }
        for (int i = 0; i < NL; ++i)
            *(v4*)&wbuf[NL * tq + i][0] = (v4){w[i][0], w[i][1], w[i][2], w[i][3]};
    }
    __syncthreads();
    if (t < 4)
        rzl[t] = __builtin_amdgcn_rcpf(scrs[0][t] + scrs[1][t] + scrs[2][t] + scrs[3][t]);
    __syncthreads();

    // ---- ctx: 4 h-groups of 128, each covers N/4 rows ----
    {
        int h = t & 127;
        int g = t >> 7;                 // 0..3
        int CH = N >> 2;                // 256 (s) or 128 (e)
        const float* Xb = X + (size_t)(g * CH) * H + h;
        const float* wb = &wbuf[g * CH][0];
        float c[4] = {0.f, 0.f, 0.f, 0.f};
        #pragma unroll 8
        for (int nn = 0; nn < CH; ++nn) {
            float x = Xb[(size_t)nn * H];
            float4 w4 = *(const float4*)(wb + nn * 4);   // broadcast b128
            c[0] += w4.x * x; c[1] += w4.y * x;
            c[2] += w4.z * x; c[3] += w4.w * x;
        }
        #pragma unroll
        for (int mj = 0; mj < 4; ++mj) part[g][mj][h] = c[mj];
    }
    __syncthreads();
    {
        int mj = t >> 7, h = t & 127;
        float s = part[0][mj][h] + part[1][mj][h] + part[2][mj][h] + part[3][mj][h];
        ctxout[(size_t)(m0 + mj) * H + h] = s * rzl[mj];
    }
}

// ---- final MLP + coherence -------------------------------------------------
__global__ __launch_bounds__(512) void k_mlp(const float* __restrict__ attender,
                                             const float* __restrict__ ctx_s,
                                             const float* __restrict__ ctx_e,
                                             const float* __restrict__ WT_lin,
                                             const float* __restrict__ b_lin,
                                             const float* __restrict__ W_coh,
                                             const float* __restrict__ b_coh,
                                             float* __restrict__ out) {
    __shared__ float feats[4][3 * H];   // 6 KB
    __shared__ float red2[8];
    int m0 = blockIdx.x * 4;
    int t  = threadIdx.x;

    for (int i = t; i < 4 * 3 * H; i += 512) {
        int r = i / (3 * H), c = i % (3 * H);
        float v;
        if (c < H)            v = attender[(size_t)(m0 + r) * H + c];
        else if (c < 2 * H)   v = ctx_s[(size_t)(m0 + r) * H + (c - H)];
        else                  v = ctx_e[(size_t)(m0 + r) * H + (c - 2 * H)];
        feats[r][c] = v;
    }
    __syncthreads();

    int a  = t & 127;
    int jm = t >> 7;
    float acc = b_lin[a];
    #pragma unroll 8
    for (int k = 0; k < 3 * H; ++k)
        acc += feats[jm][k] * WT_lin[k * H + a];
    float v = fast_tanh(acc) * W_coh[a];
    #pragma unroll
    for (int off = 32; off > 0; off >>= 1) v += __shfl_down(v, off, 64);
    if ((t & 63) == 0) red2[t >> 6] = v;
    __syncthreads();
    if (t < 4) out[m0 + t] = red2[2 * t] + red2[2 * t + 1] + b_coh[0];
}

extern "C" void kernel_launch(void* const* d_in, const int* in_sizes, int n_in,
                              void* d_out, int out_size, void* d_ws, size_t ws_size,
                              hipStream_t stream) {
    const float* stmts    = (const float*)d_in[0];
    const float* eres     = (const float*)d_in[1];
    const float* attender = (const float*)d_in[2];
    const float* Wc_s     = (const float*)d_in[3];
    const float* bc_s     = (const float*)d_in[4];
    const float* ws_s     = (const float*)d_in[5];
    const float* Wc_e     = (const float*)d_in[7];
    const float* bc_e     = (const float*)d_in[8];
    const float* ws_e     = (const float*)d_in[9];
    const float* W_lin    = (const float*)d_in[11];
    const float* b_lin    = (const float*)d_in[12];
    const float* W_coh    = (const float*)d_in[13];
    const float* b_coh    = (const float*)d_in[14];
    float* out = (float*)d_out;

    float* ws    = (float*)d_ws;
    float* WT_s1 = ws;
    float* WT_s2 = WT_s1 + H * H;
    float* WT_e1 = WT_s2 + H * H;
    float* WT_e2 = WT_e1 + H * H;
    float* WT_li = WT_e2 + H * H;             // 384*128
    float* EAT_s = WT_li + 3 * H * H;         // [H][NS]
    float* EB_s  = EAT_s + NS * H;
    float* EAT_e = EB_s + M * H;              // [H][NE]
    float* EB_e  = EAT_e + NE * H;
    float* c_s   = EB_e + M * H;              // ctx_s [M][H]
    float* c_e   = c_s + (size_t)M * H;       // ctx_e [M][H]

    k_tr<<<448, 256, 0, stream>>>(Wc_s, Wc_e, W_lin, WT_s1, WT_s2, WT_e1, WT_e2, WT_li);
    k_proj<<<608, 256, 0, stream>>>(stmts, eres, attender, WT_s1, WT_s2, WT_e1, WT_e2,
                                    bc_s, bc_e, EAT_s, EB_s, EAT_e, EB_e);
    k_score_ctx<<<512, 512, 0, stream>>>(EAT_s, EB_s, ws_s, EAT_e, EB_e, ws_e,
                                         stmts, eres, c_s, c_e);
    k_mlp<<<M / 4, 512, 0, stream>>>(attender, c_s, c_e, WT_li, b_lin, W_coh, b_coh, out);
}